// Round 1
// baseline (874.656 us; speedup 1.0000x reference)
//
#include <hip/hip_runtime.h>
#include <hip/hip_bf16.h>
#include <math.h>

typedef __attribute__((ext_vector_type(4))) float f32x4;
typedef __attribute__((ext_vector_type(8))) short s16x8;
typedef unsigned short u16;
typedef unsigned int u32;

#define CDIM 384
#define PDIM 192
#define LDIM 4096
#define BSZ  16
#define MDIM 65536
#define KD   384
#define LDSK 40   // padded LDS row stride (bf16 elems) for 32-k tiles

__device__ __forceinline__ u16 f2bf(float f) {
    u32 x = __float_as_uint(f);
    x += 0x7fffu + ((x >> 16) & 1u);
    return (u16)(x >> 16);
}

__device__ __forceinline__ float gelu_exact(float x) {
    return 0.5f * x * (1.0f + erff(x * 0.7071067811865476f));
}

// ---------------- setup: build bf16 weights + lam_bar ----------------
__global__ __launch_bounds__(256) void k_setup(
    const float* __restrict__ Lambda, const float* __restrict__ Bmat,
    const float* __restrict__ Cmat, const float* __restrict__ log_step,
    const float* __restrict__ W_enc, const float* __restrict__ W_dec,
    u16* __restrict__ Wb, u16* __restrict__ Wc, u16* __restrict__ We,
    u16* __restrict__ Wd, float* __restrict__ lam_bar)
{
    int idx = blockIdx.x * 256 + threadIdx.x;
    if (idx < 73728) {                       // Wb: B_bar^T rows [2P][C]
        int p = idx / CDIM, c = idx % CDIM;
        float st  = expf(log_step[p]);
        float lre = Lambda[2*p], lim = Lambda[2*p+1];
        float el  = expf(lre * st);
        float lbr = el * cosf(lim * st);
        float lbi = el * sinf(lim * st);
        float dd  = lre*lre + lim*lim;
        float a = lbr - 1.0f, b = lbi;
        float cr = (a * lre + b * lim) / dd; // (lam_bar-1)/lam
        float ci = (b * lre - a * lim) / dd;
        float Br = Bmat[2*(p*CDIM + c)], Bi = Bmat[2*(p*CDIM + c) + 1];
        Wb[p*KD + c]          = f2bf(cr*Br - ci*Bi);
        Wb[(PDIM + p)*KD + c] = f2bf(cr*Bi + ci*Br);
    } else if (idx < 147456) {               // Wc: [C][2P], 2*mask folded, -im
        int e = idx - 73728;
        int h = e / PDIM, p = e % PDIM;
        float st  = expf(log_step[p]);
        float lim = Lambda[2*p+1];
        float freq = st * fabsf(lim) / 6.283185307179586f;
        float sc = (freq < 0.25f) ? 2.0f : 0.0f;
        Wc[h*KD + p]        = f2bf( sc * Cmat[2*(h*PDIM + p)]);
        Wc[h*KD + PDIM + p] = f2bf(-sc * Cmat[2*(h*PDIM + p) + 1]);
    } else if (idx < 442368) {               // We: W_enc [768][384]
        int e = idx - 147456;
        We[e] = f2bf(W_enc[e]);
    } else if (idx < 589824) {               // Wd: W_dec [384][384]
        int e = idx - 442368;
        Wd[e] = f2bf(W_dec[e]);
    } else if (idx < 590016) {               // lam_bar [P][2]
        int p = idx - 589824;
        float st  = expf(log_step[p]);
        float lre = Lambda[2*p], lim = Lambda[2*p+1];
        float el  = expf(lre * st);
        lam_bar[2*p]   = el * cosf(lim * st);
        lam_bar[2*p+1] = el * sinf(lim * st);
    }
}

// ---------------- LN1 + transpose: x[B,C,L] -> fx[M,C] ----------------
__global__ __launch_bounds__(256) void k_ln1(
    const float* __restrict__ x, const float* __restrict__ g,
    const float* __restrict__ bb, float* __restrict__ fx)
{
    __shared__ float tile[CDIM * 36];  // [c][l32], stride 36 (pad)
    __shared__ float mu_sh[32], inv_sh[32];
    int b  = blockIdx.x >> 7;
    int l0 = (blockIdx.x & 127) * 32;
    int tid = threadIdx.x;
    const float* src = x + ((size_t)b * CDIM) * LDIM + l0;
    #pragma unroll
    for (int it = 0; it < 12; it++) {
        int s = it * 256 + tid;           // 3072 float4 slots
        int ch = s >> 3, c4 = (s & 7) * 4;
        float4 v = *(const float4*)(src + (size_t)ch * LDIM + c4);
        *(float4*)(tile + ch * 36 + c4) = v;
    }
    __syncthreads();
    int j = tid >> 3, k = tid & 7;        // col j of 32, 8 threads each
    float sum = 0.f, sq = 0.f;
    for (int c = k; c < CDIM; c += 8) {
        float v = tile[c * 36 + j];
        sum += v; sq += v * v;
    }
    sum += __shfl_xor(sum, 1); sq += __shfl_xor(sq, 1);
    sum += __shfl_xor(sum, 2); sq += __shfl_xor(sq, 2);
    sum += __shfl_xor(sum, 4); sq += __shfl_xor(sq, 4);
    float mu  = sum * (1.0f / CDIM);
    float var = sq * (1.0f / CDIM) - mu * mu;
    float inv = rsqrtf(var + 1e-5f);
    if (k == 0) { mu_sh[j] = mu; inv_sh[j] = inv; }
    __syncthreads();
    float* dst = fx + ((size_t)(b * LDIM + l0)) * CDIM;
    #pragma unroll
    for (int it = 0; it < 12; it++) {
        int s  = it * 256 + tid;          // 3072 float4 slots
        int cq = s % 96, jj = s / 96;
        int c  = cq * 4;
        float m2 = mu_sh[jj], iv = inv_sh[jj];
        float4 gv = *(const float4*)(g + c);
        float4 bv = *(const float4*)(bb + c);
        float4 o;
        o.x = (tile[(c+0)*36 + jj] - m2) * iv * gv.x + bv.x;
        o.y = (tile[(c+1)*36 + jj] - m2) * iv * gv.y + bv.y;
        o.z = (tile[(c+2)*36 + jj] - m2) * iv * gv.z + bv.z;
        o.w = (tile[(c+3)*36 + jj] - m2) * iv * gv.w + bv.w;
        *(float4*)(dst + (size_t)jj * CDIM + c) = o;
    }
}

// ---------------- GEMM core: C[64x64] = A[M,384] * Wt[N,384]^T ----------------
__device__ __forceinline__ void gemm_core(
    const float* __restrict__ A, const u16* __restrict__ Wt,
    int m0, int n0, u16* a_sh, u16* b_sh, f32x4 acc[4])
{
    const int tid  = threadIdx.x;
    const int wave = tid >> 6;
    const int lane = tid & 63;
    const int t16  = lane & 15;
    const int quad = lane >> 4;
    const int r    = tid >> 2;
    const int fc   = (tid & 3) << 3;
    acc[0] = (f32x4){0.f, 0.f, 0.f, 0.f};
    acc[1] = acc[0]; acc[2] = acc[0]; acc[3] = acc[0];
    const float* ap = A  + (size_t)(m0 + r) * KD + fc;
    const u16*   bp = Wt + (size_t)(n0 + r) * KD + fc;
    u16* aw = a_sh + r * LDSK + fc;
    u16* bw = b_sh + r * LDSK + fc;
    const u16* ar  = a_sh + (wave * 16 + t16) * LDSK + quad * 8;
    const u16* br0 = b_sh + t16 * LDSK + quad * 8;
    for (int kb = 0; kb < KD; kb += 32) {
        __syncthreads();
        float4 v0 = *(const float4*)(ap + kb);
        float4 v1 = *(const float4*)(ap + kb + 4);
        uint4 pv;
        pv.x = (u32)f2bf(v0.x) | ((u32)f2bf(v0.y) << 16);
        pv.y = (u32)f2bf(v0.z) | ((u32)f2bf(v0.w) << 16);
        pv.z = (u32)f2bf(v1.x) | ((u32)f2bf(v1.y) << 16);
        pv.w = (u32)f2bf(v1.z) | ((u32)f2bf(v1.w) << 16);
        *(uint4*)aw = pv;
        *(uint4*)bw = *(const uint4*)(bp + kb);
        __syncthreads();
        s16x8 af = *(const s16x8*)ar;
        #pragma unroll
        for (int j = 0; j < 4; j++) {
            s16x8 bfr = *(const s16x8*)(br0 + j * 16 * LDSK);
            acc[j] = __builtin_amdgcn_mfma_f32_16x16x32_bf16(af, bfr, acc[j], 0, 0, 0);
        }
    }
    __syncthreads();
}

// ---------------- GEMM kernels with fused epilogues ----------------
__global__ __launch_bounds__(256) void k_gemm_bu(
    const float* __restrict__ fx, const u16* __restrict__ Wb, float* __restrict__ Bu)
{
    __shared__ u16 a_sh[64 * LDSK], b_sh[64 * LDSK];
    int m0 = blockIdx.x * 64, n0 = blockIdx.y * 64;
    f32x4 acc[4];
    gemm_core(fx, Wb, m0, n0, a_sh, b_sh, acc);
    int lane = threadIdx.x & 63, wave = threadIdx.x >> 6;
    int t16 = lane & 15, quad = lane >> 4;
    #pragma unroll
    for (int j = 0; j < 4; j++)
        #pragma unroll
        for (int rr = 0; rr < 4; rr++) {
            int m = m0 + wave * 16 + quad * 4 + rr;
            int n = n0 + j * 16 + t16;
            Bu[(size_t)m * CDIM + n] = acc[j][rr];
        }
}

__global__ __launch_bounds__(256) void k_gemm_y(
    const float* __restrict__ xs, const u16* __restrict__ Wc,
    const float* __restrict__ fx, const float* __restrict__ Dv, float* __restrict__ y)
{
    __shared__ u16 a_sh[64 * LDSK], b_sh[64 * LDSK];
    int m0 = blockIdx.x * 64, n0 = blockIdx.y * 64;
    f32x4 acc[4];
    gemm_core(xs, Wc, m0, n0, a_sh, b_sh, acc);
    int lane = threadIdx.x & 63, wave = threadIdx.x >> 6;
    int t16 = lane & 15, quad = lane >> 4;
    #pragma unroll
    for (int j = 0; j < 4; j++)
        #pragma unroll
        for (int rr = 0; rr < 4; rr++) {
            int m = m0 + wave * 16 + quad * 4 + rr;
            int n = n0 + j * 16 + t16;
            float fxv = fx[(size_t)m * CDIM + n];
            float v = acc[j][rr] + Dv[n] * fxv;
            y[(size_t)m * CDIM + n] = gelu_exact(v) + fxv;
        }
}

__global__ __launch_bounds__(256) void k_gemm_z(
    const float* __restrict__ fy, const u16* __restrict__ We,
    float* __restrict__ z1, float* __restrict__ z2)
{
    __shared__ u16 a_sh[64 * LDSK], b_sh[64 * LDSK];
    int m0 = blockIdx.x * 64, n0 = blockIdx.y * 64;
    f32x4 acc[4];
    gemm_core(fy, We, m0, n0, a_sh, b_sh, acc);
    int lane = threadIdx.x & 63, wave = threadIdx.x >> 6;
    int t16 = lane & 15, quad = lane >> 4;
    #pragma unroll
    for (int j = 0; j < 4; j++)
        #pragma unroll
        for (int rr = 0; rr < 4; rr++) {
            int m = m0 + wave * 16 + quad * 4 + rr;
            int n = n0 + j * 16 + t16;
            float v = acc[j][rr];
            if (n < CDIM) z1[(size_t)m * CDIM + n] = v;
            else          z2[(size_t)m * CDIM + (n - CDIM)] = v;
        }
}

__global__ __launch_bounds__(256) void k_gemm_out(
    const float* __restrict__ zg, const u16* __restrict__ Wd,
    const float* __restrict__ fy, float* __restrict__ out)
{
    __shared__ u16 a_sh[64 * LDSK], b_sh[64 * LDSK];
    __shared__ float c_sh[64 * 65];
    int m0 = blockIdx.x * 64, n0 = blockIdx.y * 64;
    f32x4 acc[4];
    gemm_core(zg, Wd, m0, n0, a_sh, b_sh, acc);
    int tid = threadIdx.x;
    int lane = tid & 63, wave = tid >> 6;
    int t16 = lane & 15, quad = lane >> 4;
    #pragma unroll
    for (int j = 0; j < 4; j++)
        #pragma unroll
        for (int rr = 0; rr < 4; rr++) {
            int lm = wave * 16 + quad * 4 + rr;
            int ln = j * 16 + t16;
            int m = m0 + lm, n = n0 + ln;
            c_sh[ln * 65 + lm] = acc[j][rr] + fy[(size_t)m * CDIM + n];
        }
    __syncthreads();
    int b  = m0 >> 12;
    int l0 = m0 & 4095;
    int row = tid >> 2, mp = (tid & 3) * 16;
    float* dst = out + ((size_t)(b * CDIM + n0 + row)) * LDIM + l0 + mp;
    const float* srow = c_sh + row * 65 + mp;
    #pragma unroll
    for (int i = 0; i < 16; i += 4) {
        float4 v;
        v.x = srow[i]; v.y = srow[i+1]; v.z = srow[i+2]; v.w = srow[i+3];
        *(float4*)(dst + i) = v;
    }
}

// ---------------- chunked complex scan over L (chunk=64, 64 chunks/b) ----------------
__global__ __launch_bounds__(192) void k_scan_a(
    const float* __restrict__ Bu, const float* __restrict__ lam_bar,
    float* __restrict__ summ)
{
    int b = blockIdx.x >> 6, ch = blockIdx.x & 63;
    int p = threadIdx.x;
    float lr = lam_bar[2*p], li = lam_bar[2*p+1];
    float xr = 0.f, xi = 0.f;
    const float* base = Bu + (size_t)(b * LDIM + ch * 64) * CDIM;
    #pragma unroll 8
    for (int i = 0; i < 64; i++) {
        float br = base[(size_t)i * CDIM + p];
        float bi = base[(size_t)i * CDIM + PDIM + p];
        float nr = lr * xr - li * xi + br;
        float ni = lr * xi + li * xr + bi;
        xr = nr; xi = ni;
    }
    size_t o = (size_t)(b * 64 + ch) * CDIM + p;
    summ[o] = xr;
    summ[o + PDIM] = xi;
}

__global__ __launch_bounds__(256) void k_scan_b(
    const float* __restrict__ lam_bar, float* __restrict__ summ)
{
    int id = blockIdx.x * 256 + threadIdx.x;
    if (id >= BSZ * PDIM) return;
    int b = id / PDIM, p = id % PDIM;
    float ar = lam_bar[2*p], ai = lam_bar[2*p+1];
    #pragma unroll
    for (int s = 0; s < 6; s++) {       // lam_bar^64
        float nr = ar * ar - ai * ai, ni = 2.f * ar * ai;
        ar = nr; ai = ni;
    }
    float cr = 0.f, ci = 0.f;
    for (int ch = 0; ch < 64; ch++) {
        size_t o = (size_t)(b * 64 + ch) * CDIM + p;
        float sr = summ[o], si = summ[o + PDIM];
        summ[o] = cr; summ[o + PDIM] = ci;   // exclusive carry-in
        float nr = ar * cr - ai * ci + sr;
        float ni = ar * ci + ai * cr + si;
        cr = nr; ci = ni;
    }
}

__global__ __launch_bounds__(192) void k_scan_c(
    float* __restrict__ Bu, const float* __restrict__ lam_bar,
    const float* __restrict__ summ)
{
    int b = blockIdx.x >> 6, ch = blockIdx.x & 63;
    int p = threadIdx.x;
    float lr = lam_bar[2*p], li = lam_bar[2*p+1];
    size_t oc = (size_t)(b * 64 + ch) * CDIM + p;
    float xr = summ[oc], xi = summ[oc + PDIM];
    float* base = Bu + (size_t)(b * LDIM + ch * 64) * CDIM;
    #pragma unroll 8
    for (int i = 0; i < 64; i++) {
        float br = base[(size_t)i * CDIM + p];
        float bi = base[(size_t)i * CDIM + PDIM + p];
        float nr = lr * xr - li * xi + br;
        float ni = lr * xi + li * xr + bi;
        xr = nr; xi = ni;
        base[(size_t)i * CDIM + p] = xr;
        base[(size_t)i * CDIM + PDIM + p] = xi;
    }
}

// ---------------- LN2 (rows contiguous) ----------------
__global__ __launch_bounds__(256) void k_ln2(
    const float* __restrict__ y, const float* __restrict__ g,
    const float* __restrict__ bb, float* __restrict__ fy)
{
    int wave = threadIdx.x >> 6, lane = threadIdx.x & 63;
    size_t m = (size_t)blockIdx.x * 4 + wave;
    const float* row = y + m * CDIM;
    float v[6];
    float sum = 0.f, sq = 0.f;
    #pragma unroll
    for (int i = 0; i < 6; i++) {
        v[i] = row[lane + 64 * i];
        sum += v[i]; sq += v[i] * v[i];
    }
    #pragma unroll
    for (int o = 1; o < 64; o <<= 1) {
        sum += __shfl_xor(sum, o); sq += __shfl_xor(sq, o);
    }
    float mu  = sum * (1.0f / CDIM);
    float var = sq * (1.0f / CDIM) - mu * mu;
    float inv = rsqrtf(var + 1e-5f);
    float* dst = fy + m * CDIM;
    #pragma unroll
    for (int i = 0; i < 6; i++) {
        int c = lane + 64 * i;
        dst[c] = (v[i] - mu) * inv * g[c] + bb[c];
    }
}

// ---------------- GEGLU: z1 *= gelu(z2) ----------------
__global__ __launch_bounds__(256) void k_geglu(
    float* __restrict__ z1, const float* __restrict__ z2)
{
    size_t i = ((size_t)blockIdx.x * 256 + threadIdx.x) * 4;
    if (i >= (size_t)MDIM * CDIM) return;
    float4 a = *(float4*)(z1 + i);
    float4 gv = *(const float4*)(z2 + i);
    a.x *= gelu_exact(gv.x);
    a.y *= gelu_exact(gv.y);
    a.z *= gelu_exact(gv.z);
    a.w *= gelu_exact(gv.w);
    *(float4*)(z1 + i) = a;
}

extern "C" void kernel_launch(void* const* d_in, const int* in_sizes, int n_in,
                              void* d_out, int out_size, void* d_ws, size_t ws_size,
                              hipStream_t stream)
{
    const float* x        = (const float*)d_in[0];
    const float* ln1_g    = (const float*)d_in[1];
    const float* ln1_b    = (const float*)d_in[2];
    const float* Lambda   = (const float*)d_in[3];
    const float* Bmat     = (const float*)d_in[4];
    const float* Cmat     = (const float*)d_in[5];
    const float* Dvec     = (const float*)d_in[6];
    const float* log_step = (const float*)d_in[7];
    const float* ln2_g    = (const float*)d_in[8];
    const float* ln2_b    = (const float*)d_in[9];
    const float* W_enc    = (const float*)d_in[10];
    const float* W_dec    = (const float*)d_in[11];

    char* ws = (char*)d_ws;
    const size_t SLOT = (size_t)MDIM * CDIM * 4;   // 100,663,296 B
    float* fx = (float*)(ws);                      // fx, later fy
    float* bu = (float*)(ws + SLOT);               // Bu -> xs -> z1(zg)
    float* yb = (float*)d_out;                     // y -> z2 (d_out reused as scratch)
    char*  wbase = ws + 2 * SLOT;
    u16* Wb = (u16*)(wbase);
    u16* Wc = (u16*)(wbase + 294912);
    u16* We = (u16*)(wbase + 589824);
    u16* Wd = (u16*)(wbase + 1179648);
    float* lam_bar = (float*)(wbase + 1474560);
    float* summ    = (float*)(wbase + 1476096);    // 16*64*384 fp32
    float* out = (float*)d_out;

    k_setup<<<2305, 256, 0, stream>>>(Lambda, Bmat, Cmat, log_step, W_enc, W_dec,
                                      Wb, Wc, We, Wd, lam_bar);
    k_ln1<<<2048, 256, 0, stream>>>(x, ln1_g, ln1_b, fx);
    k_gemm_bu<<<dim3(1024, 6), 256, 0, stream>>>(fx, Wb, bu);
    k_scan_a<<<1024, 192, 0, stream>>>(bu, lam_bar, summ);
    k_scan_b<<<12, 256, 0, stream>>>(lam_bar, summ);
    k_scan_c<<<1024, 192, 0, stream>>>(bu, lam_bar, summ);
    k_gemm_y<<<dim3(1024, 6), 256, 0, stream>>>(bu, Wc, fx, Dvec, yb);
    k_ln2<<<16384, 256, 0, stream>>>(yb, ln2_g, ln2_b, fx);       // fy -> fx slot
    k_gemm_z<<<dim3(1024, 12), 256, 0, stream>>>(fx, We, bu, yb); // z1->bu, z2->yb
    k_geglu<<<24576, 256, 0, stream>>>(bu, yb);
    k_gemm_out<<<dim3(1024, 6), 256, 0, stream>>>(bu, Wd, fx, out);
}

// Round 2
// 518.000 us; speedup vs baseline: 1.6885x; 1.6885x over previous
//
#include <hip/hip_runtime.h>
#include <hip/hip_bf16.h>
#include <math.h>

typedef __attribute__((ext_vector_type(4))) float f32x4;
typedef __attribute__((ext_vector_type(8))) short s16x8;
typedef unsigned short u16;
typedef unsigned int u32;

#define CDIM 384
#define PDIM 192
#define LDIM 4096
#define BSZ  16
#define MDIM 65536
#define KD   384
#define BM 128
#define BN 128
#define BK 32

__device__ __forceinline__ u16 f2bf(float f) {
    u32 x = __float_as_uint(f);
    x += 0x7fffu + ((x >> 16) & 1u);
    return (u16)(x >> 16);
}
__device__ __forceinline__ float bf2f(u16 v) {
    return __uint_as_float(((u32)v) << 16);
}
__device__ __forceinline__ float gelu_exact(float x) {
    return 0.5f * x * (1.0f + erff(x * 0.7071067811865476f));
}
__device__ __forceinline__ void gld_lds16(const u16* g, u16* l) {
    __builtin_amdgcn_global_load_lds(
        (const __attribute__((address_space(1))) void*)g,
        (__attribute__((address_space(3))) void*)l, 16, 0, 0);
}

// ---------------- setup: build bf16 weights + lam_bar ----------------
__global__ __launch_bounds__(256) void k_setup(
    const float* __restrict__ Lambda, const float* __restrict__ Bmat,
    const float* __restrict__ Cmat, const float* __restrict__ log_step,
    const float* __restrict__ W_enc, const float* __restrict__ W_dec,
    u16* __restrict__ Wb, u16* __restrict__ Wc, u16* __restrict__ We,
    u16* __restrict__ Wd, float* __restrict__ lam_bar)
{
    int idx = blockIdx.x * 256 + threadIdx.x;
    if (idx < 73728) {                       // Wb: B_bar^T rows [2P][C]
        int p = idx / CDIM, c = idx % CDIM;
        float st  = expf(log_step[p]);
        float lre = Lambda[2*p], lim = Lambda[2*p+1];
        float el  = expf(lre * st);
        float lbr = el * cosf(lim * st);
        float lbi = el * sinf(lim * st);
        float dd  = lre*lre + lim*lim;
        float a = lbr - 1.0f, b = lbi;
        float cr = (a * lre + b * lim) / dd; // (lam_bar-1)/lam
        float ci = (b * lre - a * lim) / dd;
        float Br = Bmat[2*(p*CDIM + c)], Bi = Bmat[2*(p*CDIM + c) + 1];
        Wb[p*KD + c]          = f2bf(cr*Br - ci*Bi);
        Wb[(PDIM + p)*KD + c] = f2bf(cr*Bi + ci*Br);
    } else if (idx < 147456) {               // Wc: [C][2P], 2*mask folded, -im
        int e = idx - 73728;
        int h = e / PDIM, p = e % PDIM;
        float st  = expf(log_step[p]);
        float lim = Lambda[2*p+1];
        float freq = st * fabsf(lim) / 6.283185307179586f;
        float sc = (freq < 0.25f) ? 2.0f : 0.0f;
        Wc[h*KD + p]        = f2bf( sc * Cmat[2*(h*PDIM + p)]);
        Wc[h*KD + PDIM + p] = f2bf(-sc * Cmat[2*(h*PDIM + p) + 1]);
    } else if (idx < 442368) {               // We: W_enc [768][384]
        int e = idx - 147456;
        We[e] = f2bf(W_enc[e]);
    } else if (idx < 589824) {               // Wd: W_dec [384][384]
        int e = idx - 442368;
        Wd[e] = f2bf(W_dec[e]);
    } else if (idx < 590016) {               // lam_bar [P][2]
        int p = idx - 589824;
        float st  = expf(log_step[p]);
        float lre = Lambda[2*p], lim = Lambda[2*p+1];
        float el  = expf(lre * st);
        lam_bar[2*p]   = el * cosf(lim * st);
        lam_bar[2*p+1] = el * sinf(lim * st);
    }
}

// ---------------- LN1 + transpose: x[B,C,L] fp32 -> fx[M,C] bf16 ----------------
__global__ __launch_bounds__(256) void k_ln1(
    const float* __restrict__ x, const float* __restrict__ g,
    const float* __restrict__ bb, u16* __restrict__ fx)
{
    __shared__ float tile[CDIM * 36];  // [c][l32], stride 36 (pad)
    __shared__ float mu_sh[32], inv_sh[32];
    int b  = blockIdx.x >> 7;
    int l0 = (blockIdx.x & 127) * 32;
    int tid = threadIdx.x;
    const float* src = x + ((size_t)b * CDIM) * LDIM + l0;
    #pragma unroll
    for (int it = 0; it < 12; it++) {
        int s = it * 256 + tid;           // 3072 float4 slots
        int ch = s >> 3, c4 = (s & 7) * 4;
        float4 v = *(const float4*)(src + (size_t)ch * LDIM + c4);
        *(float4*)(tile + ch * 36 + c4) = v;
    }
    __syncthreads();
    int j = tid >> 3, k = tid & 7;        // col j of 32, 8 threads each
    float sum = 0.f, sq = 0.f;
    for (int c = k; c < CDIM; c += 8) {
        float v = tile[c * 36 + j];
        sum += v; sq += v * v;
    }
    sum += __shfl_xor(sum, 1); sq += __shfl_xor(sq, 1);
    sum += __shfl_xor(sum, 2); sq += __shfl_xor(sq, 2);
    sum += __shfl_xor(sum, 4); sq += __shfl_xor(sq, 4);
    float mu  = sum * (1.0f / CDIM);
    float var = sq * (1.0f / CDIM) - mu * mu;
    float inv = rsqrtf(var + 1e-5f);
    if (k == 0) { mu_sh[j] = mu; inv_sh[j] = inv; }
    __syncthreads();
    u16* dst = fx + ((size_t)(b * LDIM + l0)) * CDIM;
    #pragma unroll
    for (int it = 0; it < 12; it++) {
        int s  = it * 256 + tid;          // 3072 slots of 4 channels
        int cq = s % 96, jj = s / 96;
        int c  = cq * 4;
        float m2 = mu_sh[jj], iv = inv_sh[jj];
        float4 gv = *(const float4*)(g + c);
        float4 bv = *(const float4*)(bb + c);
        ushort4 o;
        o.x = f2bf((tile[(c+0)*36 + jj] - m2) * iv * gv.x + bv.x);
        o.y = f2bf((tile[(c+1)*36 + jj] - m2) * iv * gv.y + bv.y);
        o.z = f2bf((tile[(c+2)*36 + jj] - m2) * iv * gv.z + bv.z);
        o.w = f2bf((tile[(c+3)*36 + jj] - m2) * iv * gv.w + bv.w);
        *(ushort4*)(dst + (size_t)jj * CDIM + c) = o;
    }
}

// ---------------- 128x128 GEMM core, global_load_lds staging, swizzled LDS ----------------
// A: bf16 [M][lda] row-major; Bw: bf16 [N][KD] row-major (pre-transposed weights).
// SWAP=false: acc[i][j] row=m (quad*4+rr), col=n (t16).
// SWAP=true : acc[i][j] row=n (quad*4+rr), col=m (t16)  (computes C^T tiles).
template<bool SWAP>
__device__ __forceinline__ void gemm_core(
    const u16* __restrict__ A, int lda, const u16* __restrict__ Bw,
    int m0, int n0, u16* a_sh, u16* b_sh, f32x4 acc[4][4])
{
    const int tid  = threadIdx.x;
    const int w    = tid >> 6, lane = tid & 63;
    const int t16  = lane & 15, quad = lane >> 4;
    const int wm   = w >> 1,   wn   = w & 1;
    // staging: wave w covers rows w*32 .. w*32+31 (two 16-row issues)
    const int lr  = lane >> 2;                       // row within 16-row issue
    const int cbg = (lane & 3) ^ ((lane >> 3) & 3);  // swizzled col-block
    const u16* gA0 = A  + (size_t)(m0 + w*32 + lr) * lda + cbg*8;
    const u16* gA1 = gA0 + (size_t)16 * lda;
    const u16* gB0 = Bw + (size_t)(n0 + w*32 + lr) * KD + cbg*8;
    const u16* gB1 = gB0 + (size_t)16 * KD;
    u16* lA0 = a_sh + (w*32) * BK;                   // wave-uniform LDS bases
    u16* lA1 = lA0 + 16*BK;
    u16* lB0 = b_sh + (w*32) * BK;
    u16* lB1 = lB0 + 16*BK;
    // fragment read: row r wants col-block quad at slot quad ^ ((r>>1)&3);
    // r = (16-mult) + t16 so the swizzle term reduces to (t16>>1)&3
    const int pos = (quad ^ ((t16 >> 1) & 3)) * 8;
    const u16* ard = a_sh + (wm*64 + t16) * BK + pos;
    const u16* brd = b_sh + (wn*64 + t16) * BK + pos;
    #pragma unroll
    for (int i = 0; i < 4; i++)
        #pragma unroll
        for (int j = 0; j < 4; j++) acc[i][j] = (f32x4){0.f,0.f,0.f,0.f};
    for (int kb = 0; kb < KD; kb += BK) {
        __syncthreads();
        gld_lds16(gA0 + kb, lA0);
        gld_lds16(gA1 + kb, lA1);
        gld_lds16(gB0 + kb, lB0);
        gld_lds16(gB1 + kb, lB1);
        __syncthreads();
        s16x8 af[4], bfr[4];
        #pragma unroll
        for (int i = 0; i < 4; i++) af[i]  = *(const s16x8*)(ard + i*16*BK);
        #pragma unroll
        for (int j = 0; j < 4; j++) bfr[j] = *(const s16x8*)(brd + j*16*BK);
        #pragma unroll
        for (int i = 0; i < 4; i++)
            #pragma unroll
            for (int j = 0; j < 4; j++) {
                if (SWAP)
                    acc[i][j] = __builtin_amdgcn_mfma_f32_16x16x32_bf16(bfr[j], af[i], acc[i][j], 0,0,0);
                else
                    acc[i][j] = __builtin_amdgcn_mfma_f32_16x16x32_bf16(af[i], bfr[j], acc[i][j], 0,0,0);
            }
    }
}

// ---------------- GEMM kernels with fused epilogues ----------------
__global__ __launch_bounds__(256) void k_gemm_bu(
    const u16* __restrict__ fx, const u16* __restrict__ Wb, u16* __restrict__ Bu)
{
    __shared__ __align__(16) u16 a_sh[BM*BK], b_sh[BN*BK];
    int m0 = blockIdx.x * BM, n0 = blockIdx.y * BN;
    f32x4 acc[4][4];
    gemm_core<false>(fx, CDIM, Wb, m0, n0, a_sh, b_sh, acc);
    int lane = threadIdx.x & 63, w = threadIdx.x >> 6;
    int t16 = lane & 15, quad = lane >> 4, wm = w >> 1, wn = w & 1;
    #pragma unroll
    for (int i = 0; i < 4; i++)
        #pragma unroll
        for (int j = 0; j < 4; j++)
            #pragma unroll
            for (int rr = 0; rr < 4; rr++) {
                int m = m0 + wm*64 + i*16 + quad*4 + rr;
                int n = n0 + wn*64 + j*16 + t16;
                Bu[(size_t)m * CDIM + n] = f2bf(acc[i][j][rr]);
            }
}

__global__ __launch_bounds__(256) void k_gemm_y(
    const u16* __restrict__ xs, const u16* __restrict__ Wc,
    const u16* __restrict__ fx, const float* __restrict__ Dv, u16* __restrict__ y)
{
    __shared__ __align__(16) u16 a_sh[BM*BK], b_sh[BN*BK];
    int m0 = blockIdx.x * BM, n0 = blockIdx.y * BN;
    f32x4 acc[4][4];
    gemm_core<false>(xs, CDIM, Wc, m0, n0, a_sh, b_sh, acc);
    int lane = threadIdx.x & 63, w = threadIdx.x >> 6;
    int t16 = lane & 15, quad = lane >> 4, wm = w >> 1, wn = w & 1;
    float dv[4];
    #pragma unroll
    for (int j = 0; j < 4; j++) dv[j] = Dv[n0 + wn*64 + j*16 + t16];
    #pragma unroll
    for (int i = 0; i < 4; i++)
        #pragma unroll
        for (int j = 0; j < 4; j++)
            #pragma unroll
            for (int rr = 0; rr < 4; rr++) {
                int m = m0 + wm*64 + i*16 + quad*4 + rr;
                int n = n0 + wn*64 + j*16 + t16;
                float fxv = bf2f(fx[(size_t)m * CDIM + n]);
                float v = acc[i][j][rr] + dv[j] * fxv;
                y[(size_t)m * CDIM + n] = f2bf(gelu_exact(v) + fxv);
            }
}

__global__ __launch_bounds__(256) void k_gemm_z(
    const u16* __restrict__ fy, const u16* __restrict__ We, u16* __restrict__ z)
{
    __shared__ __align__(16) u16 a_sh[BM*BK], b_sh[BN*BK];
    int m0 = blockIdx.x * BM, n0 = blockIdx.y * BN;
    f32x4 acc[4][4];
    gemm_core<false>(fy, CDIM, We, m0, n0, a_sh, b_sh, acc);
    int lane = threadIdx.x & 63, w = threadIdx.x >> 6;
    int t16 = lane & 15, quad = lane >> 4, wm = w >> 1, wn = w & 1;
    #pragma unroll
    for (int i = 0; i < 4; i++)
        #pragma unroll
        for (int j = 0; j < 4; j++)
            #pragma unroll
            for (int rr = 0; rr < 4; rr++) {
                int m = m0 + wm*64 + i*16 + quad*4 + rr;
                int n = n0 + wn*64 + j*16 + t16;     // 0..767
                z[(size_t)m * 768 + n] = f2bf(acc[i][j][rr]);
            }
}

__global__ __launch_bounds__(256) void k_gemm_out(
    const u16* __restrict__ zg, const u16* __restrict__ Wd,
    const u16* __restrict__ fy, float* __restrict__ out)
{
    __shared__ __align__(16) u16 a_sh[BM*BK], b_sh[BN*BK];
    int m0 = blockIdx.x * BM, n0 = blockIdx.y * BN;
    f32x4 acc[4][4];
    gemm_core<true>(zg, 768, Wd, m0, n0, a_sh, b_sh, acc);  // zg = z1-half, lda=768
    int lane = threadIdx.x & 63, w = threadIdx.x >> 6;
    int t16 = lane & 15, quad = lane >> 4, wm = w >> 1, wn = w & 1;
    int b = m0 >> 12;
    #pragma unroll
    for (int i = 0; i < 4; i++)
        #pragma unroll
        for (int j = 0; j < 4; j++)
            #pragma unroll
            for (int rr = 0; rr < 4; rr++) {
                int nn = n0 + wn*64 + j*16 + quad*4 + rr;
                int mm = m0 + wm*64 + i*16 + t16;
                float fyv = bf2f(fy[(size_t)mm * CDIM + nn]);
                int l = mm & 4095;
                out[((size_t)(b * CDIM + nn)) * LDIM + l] = acc[i][j][rr] + fyv;
            }
}

// ---------------- chunked complex scan over L (chunk=64, 64 chunks/b) ----------------
__global__ __launch_bounds__(192) void k_scan_a(
    const u16* __restrict__ Bu, const float* __restrict__ lam_bar,
    float* __restrict__ summ)
{
    int b = blockIdx.x >> 6, ch = blockIdx.x & 63;
    int p = threadIdx.x;
    float lr = lam_bar[2*p], li = lam_bar[2*p+1];
    float xr = 0.f, xi = 0.f;
    const u16* base = Bu + (size_t)(b * LDIM + ch * 64) * CDIM;
    #pragma unroll 8
    for (int i = 0; i < 64; i++) {
        float br = bf2f(base[(size_t)i * CDIM + p]);
        float bi = bf2f(base[(size_t)i * CDIM + PDIM + p]);
        float nr = lr * xr - li * xi + br;
        float ni = lr * xi + li * xr + bi;
        xr = nr; xi = ni;
    }
    size_t o = (size_t)(b * 64 + ch) * CDIM + p;
    summ[o] = xr;
    summ[o + PDIM] = xi;
}

__global__ __launch_bounds__(256) void k_scan_b(
    const float* __restrict__ lam_bar, float* __restrict__ summ)
{
    int id = blockIdx.x * 256 + threadIdx.x;
    if (id >= BSZ * PDIM) return;
    int b = id / PDIM, p = id % PDIM;
    float ar = lam_bar[2*p], ai = lam_bar[2*p+1];
    #pragma unroll
    for (int s = 0; s < 6; s++) {       // lam_bar^64
        float nr = ar * ar - ai * ai, ni = 2.f * ar * ai;
        ar = nr; ai = ni;
    }
    float cr = 0.f, ci = 0.f;
    #pragma unroll 4
    for (int ch = 0; ch < 64; ch++) {
        size_t o = (size_t)(b * 64 + ch) * CDIM + p;
        float sr = summ[o], si = summ[o + PDIM];
        summ[o] = cr; summ[o + PDIM] = ci;   // exclusive carry-in
        float nr = ar * cr - ai * ci + sr;
        float ni = ar * ci + ai * cr + si;
        cr = nr; ci = ni;
    }
}

__global__ __launch_bounds__(192) void k_scan_c(
    u16* __restrict__ Bu, const float* __restrict__ lam_bar,
    const float* __restrict__ summ)
{
    int b = blockIdx.x >> 6, ch = blockIdx.x & 63;
    int p = threadIdx.x;
    float lr = lam_bar[2*p], li = lam_bar[2*p+1];
    size_t oc = (size_t)(b * 64 + ch) * CDIM + p;
    float xr = summ[oc], xi = summ[oc + PDIM];
    u16* base = Bu + (size_t)(b * LDIM + ch * 64) * CDIM;
    #pragma unroll 8
    for (int i = 0; i < 64; i++) {
        float br = bf2f(base[(size_t)i * CDIM + p]);
        float bi = bf2f(base[(size_t)i * CDIM + PDIM + p]);
        float nr = lr * xr - li * xi + br;
        float ni = lr * xi + li * xr + bi;
        xr = nr; xi = ni;
        base[(size_t)i * CDIM + p] = f2bf(xr);
        base[(size_t)i * CDIM + PDIM + p] = f2bf(xi);
    }
}

// ---------------- LN2 (rows contiguous, bf16 in/out) ----------------
__global__ __launch_bounds__(256) void k_ln2(
    const u16* __restrict__ y, const float* __restrict__ g,
    const float* __restrict__ bb, u16* __restrict__ fy)
{
    int w = threadIdx.x >> 6, lane = threadIdx.x & 63;
    size_t m = (size_t)blockIdx.x * 4 + w;
    const u16* row = y + m * CDIM;
    float v[6];
    float sum = 0.f, sq = 0.f;
    #pragma unroll
    for (int i = 0; i < 6; i++) {
        v[i] = bf2f(row[lane + 64 * i]);
        sum += v[i]; sq += v[i] * v[i];
    }
    #pragma unroll
    for (int o = 1; o < 64; o <<= 1) {
        sum += __shfl_xor(sum, o); sq += __shfl_xor(sq, o);
    }
    float mu  = sum * (1.0f / CDIM);
    float var = sq * (1.0f / CDIM) - mu * mu;
    float inv = rsqrtf(var + 1e-5f);
    u16* dst = fy + m * CDIM;
    #pragma unroll
    for (int i = 0; i < 6; i++) {
        int c = lane + 64 * i;
        dst[c] = f2bf((v[i] - mu) * inv * g[c] + bb[c]);
    }
}

// ---------------- GEGLU in place: z1 <- z1 * gelu(z2) ----------------
__global__ __launch_bounds__(256) void k_geglu(u16* __restrict__ z)
{
    int t = blockIdx.x * 256 + threadIdx.x;   // 65536*48 threads, 8 elems each
    int m = t / 48;
    int c = (t % 48) * 8;
    u16* zr = z + (size_t)m * 768;
    uint4 a  = *(const uint4*)(zr + c);
    uint4 g2 = *(const uint4*)(zr + 384 + c);
    u32 aw[4] = {a.x, a.y, a.z, a.w};
    u32 gw[4] = {g2.x, g2.y, g2.z, g2.w};
    u32 rw[4];
    #pragma unroll
    for (int q = 0; q < 4; q++) {
        float a0 = bf2f((u16)(aw[q] & 0xffffu)), a1 = bf2f((u16)(aw[q] >> 16));
        float g0 = bf2f((u16)(gw[q] & 0xffffu)), g1 = bf2f((u16)(gw[q] >> 16));
        float r0 = a0 * gelu_exact(g0), r1 = a1 * gelu_exact(g1);
        rw[q] = (u32)f2bf(r0) | ((u32)f2bf(r1) << 16);
    }
    uint4 o = {rw[0], rw[1], rw[2], rw[3]};
    *(uint4*)(zr + c) = o;
}

extern "C" void kernel_launch(void* const* d_in, const int* in_sizes, int n_in,
                              void* d_out, int out_size, void* d_ws, size_t ws_size,
                              hipStream_t stream)
{
    const float* x        = (const float*)d_in[0];
    const float* ln1_g    = (const float*)d_in[1];
    const float* ln1_b    = (const float*)d_in[2];
    const float* Lambda   = (const float*)d_in[3];
    const float* Bmat     = (const float*)d_in[4];
    const float* Cmat     = (const float*)d_in[5];
    const float* Dvec     = (const float*)d_in[6];
    const float* log_step = (const float*)d_in[7];
    const float* ln2_g    = (const float*)d_in[8];
    const float* ln2_b    = (const float*)d_in[9];
    const float* W_enc    = (const float*)d_in[10];
    const float* W_dec    = (const float*)d_in[11];

    char* ws = (char*)d_ws;
    const size_t HBF = (size_t)MDIM * CDIM * 2;    // 50,331,648 B (bf16 [M,384])
    u16* fx = (u16*)(ws);                          // fx bf16
    u16* fy = (u16*)(ws + HBF);                    // fy bf16
    u16* bu = (u16*)(ws + 2 * HBF);                // Bu/xs bf16 [M,384]
    u16* z  = (u16*)(ws + 2 * HBF);                // z bf16 [M,768] (overlaps bu; bu dead)
    char* wbase = ws + 4 * HBF;                    // z ends exactly at 4*HBF
    u16* Wb = (u16*)(wbase);
    u16* Wc = (u16*)(wbase + 294912);
    u16* We = (u16*)(wbase + 589824);
    u16* Wd = (u16*)(wbase + 1179648);
    float* lam_bar = (float*)(wbase + 1474560);
    float* summ    = (float*)(wbase + 1476096);    // 16*64*384 fp32
    u16* yb  = (u16*)d_out;                        // y bf16 scratch inside d_out
    float* out = (float*)d_out;

    k_setup<<<2305, 256, 0, stream>>>(Lambda, Bmat, Cmat, log_step, W_enc, W_dec,
                                      Wb, Wc, We, Wd, lam_bar);
    k_ln1<<<2048, 256, 0, stream>>>(x, ln1_g, ln1_b, fx);
    k_gemm_bu<<<dim3(512, 3), 256, 0, stream>>>(fx, Wb, bu);
    k_scan_a<<<1024, 192, 0, stream>>>(bu, lam_bar, summ);
    k_scan_b<<<12, 256, 0, stream>>>(lam_bar, summ);
    k_scan_c<<<1024, 192, 0, stream>>>(bu, lam_bar, summ);
    k_gemm_y<<<dim3(512, 3), 256, 0, stream>>>(bu, Wc, fx, Dvec, yb);
    k_ln2<<<16384, 256, 0, stream>>>(yb, ln2_g, ln2_b, fy);
    k_gemm_z<<<dim3(512, 6), 256, 0, stream>>>(fy, We, z);
    k_geglu<<<12288, 256, 0, stream>>>(z);
    k_gemm_out<<<dim3(512, 3), 256, 0, stream>>>(z, Wd, fy, out);
}

// Round 3
// 472.612 us; speedup vs baseline: 1.8507x; 1.0960x over previous
//
#include <hip/hip_runtime.h>
#include <hip/hip_bf16.h>
#include <math.h>

typedef __attribute__((ext_vector_type(4))) float f32x4;
typedef __attribute__((ext_vector_type(8))) short s16x8;
typedef unsigned short u16;
typedef unsigned int u32;

#define CDIM 384
#define PDIM 192
#define LDIM 4096
#define BSZ  16
#define MDIM 65536
#define KD   384
#define BM 128
#define BN 128
#define BK 32

__device__ __forceinline__ u16 f2bf(float f) {
    u32 x = __float_as_uint(f);
    x += 0x7fffu + ((x >> 16) & 1u);
    return (u16)(x >> 16);
}
__device__ __forceinline__ float bf2f(u16 v) {
    return __uint_as_float(((u32)v) << 16);
}
__device__ __forceinline__ float gelu_exact(float x) {   // setup only (cold)
    return 0.5f * x * (1.0f + erff(x * 0.7071067811865476f));
}
// tanh-form gelu as a single sigmoid: x * sigmoid(1.59577*x*(1+0.044715x^2))
// max abs err vs exact gelu ~2e-3 — far under bf16 epilogue noise here.
__device__ __forceinline__ float gelu_fast(float x) {
    float w = -1.5957691216f * x * (1.0f + 0.044715f * x * x);
    return x / (1.0f + __expf(w));
}
__device__ __forceinline__ void gld_lds16(const u16* g, u16* l) {
    __builtin_amdgcn_global_load_lds(
        (const __attribute__((address_space(1))) void*)g,
        (__attribute__((address_space(3))) void*)l, 16, 0, 0);
}

// ---------------- setup: build bf16 weights + lam_bar ----------------
__global__ __launch_bounds__(256) void k_setup(
    const float* __restrict__ Lambda, const float* __restrict__ Bmat,
    const float* __restrict__ Cmat, const float* __restrict__ log_step,
    const float* __restrict__ W_enc, const float* __restrict__ W_dec,
    u16* __restrict__ Wb, u16* __restrict__ Wc, u16* __restrict__ We,
    u16* __restrict__ Wd, float* __restrict__ lam_bar)
{
    int idx = blockIdx.x * 256 + threadIdx.x;
    if (idx < 73728) {                       // Wb: B_bar^T rows [2P][C]
        int p = idx / CDIM, c = idx % CDIM;
        float st  = expf(log_step[p]);
        float lre = Lambda[2*p], lim = Lambda[2*p+1];
        float el  = expf(lre * st);
        float lbr = el * cosf(lim * st);
        float lbi = el * sinf(lim * st);
        float dd  = lre*lre + lim*lim;
        float a = lbr - 1.0f, b = lbi;
        float cr = (a * lre + b * lim) / dd; // (lam_bar-1)/lam
        float ci = (b * lre - a * lim) / dd;
        float Br = Bmat[2*(p*CDIM + c)], Bi = Bmat[2*(p*CDIM + c) + 1];
        Wb[p*KD + c]          = f2bf(cr*Br - ci*Bi);
        Wb[(PDIM + p)*KD + c] = f2bf(cr*Bi + ci*Br);
    } else if (idx < 147456) {               // Wc: [C][2P], 2*mask folded, -im
        int e = idx - 73728;
        int h = e / PDIM, p = e % PDIM;
        float st  = expf(log_step[p]);
        float lim = Lambda[2*p+1];
        float freq = st * fabsf(lim) / 6.283185307179586f;
        float sc = (freq < 0.25f) ? 2.0f : 0.0f;
        Wc[h*KD + p]        = f2bf( sc * Cmat[2*(h*PDIM + p)]);
        Wc[h*KD + PDIM + p] = f2bf(-sc * Cmat[2*(h*PDIM + p) + 1]);
    } else if (idx < 442368) {               // We: W_enc [768][384]
        int e = idx - 147456;
        We[e] = f2bf(W_enc[e]);
    } else if (idx < 589824) {               // Wd: W_dec [384][384]
        int e = idx - 442368;
        Wd[e] = f2bf(W_dec[e]);
    } else if (idx < 590016) {               // lam_bar [P][2]
        int p = idx - 589824;
        float st  = expf(log_step[p]);
        float lre = Lambda[2*p], lim = Lambda[2*p+1];
        float el  = expf(lre * st);
        lam_bar[2*p]   = el * cosf(lim * st);
        lam_bar[2*p+1] = el * sinf(lim * st);
    }
}

// ---------------- LN1 + transpose: x[B,C,L] fp32 -> fx[M,C] bf16 ----------------
__global__ __launch_bounds__(256) void k_ln1(
    const float* __restrict__ x, const float* __restrict__ g,
    const float* __restrict__ bb, u16* __restrict__ fx)
{
    __shared__ float tile[CDIM * 36];  // [c][l32], stride 36 (pad)
    __shared__ float mu_sh[32], inv_sh[32];
    int b  = blockIdx.x >> 7;
    int l0 = (blockIdx.x & 127) * 32;
    int tid = threadIdx.x;
    const float* src = x + ((size_t)b * CDIM) * LDIM + l0;
    #pragma unroll
    for (int it = 0; it < 12; it++) {
        int s = it * 256 + tid;           // 3072 float4 slots
        int ch = s >> 3, c4 = (s & 7) * 4;
        float4 v = *(const float4*)(src + (size_t)ch * LDIM + c4);
        *(float4*)(tile + ch * 36 + c4) = v;
    }
    __syncthreads();
    int j = tid >> 3, k = tid & 7;        // col j of 32, 8 threads each
    float sum = 0.f, sq = 0.f;
    for (int c = k; c < CDIM; c += 8) {
        float v = tile[c * 36 + j];
        sum += v; sq += v * v;
    }
    sum += __shfl_xor(sum, 1); sq += __shfl_xor(sq, 1);
    sum += __shfl_xor(sum, 2); sq += __shfl_xor(sq, 2);
    sum += __shfl_xor(sum, 4); sq += __shfl_xor(sq, 4);
    float mu  = sum * (1.0f / CDIM);
    float var = sq * (1.0f / CDIM) - mu * mu;
    float inv = rsqrtf(var + 1e-5f);
    if (k == 0) { mu_sh[j] = mu; inv_sh[j] = inv; }
    __syncthreads();
    u16* dst = fx + ((size_t)(b * LDIM + l0)) * CDIM;
    #pragma unroll
    for (int it = 0; it < 12; it++) {
        int s  = it * 256 + tid;          // 3072 slots of 4 channels
        int cq = s % 96, jj = s / 96;
        int c  = cq * 4;
        float m2 = mu_sh[jj], iv = inv_sh[jj];
        float4 gv = *(const float4*)(g + c);
        float4 bv = *(const float4*)(bb + c);
        ushort4 o;
        o.x = f2bf((tile[(c+0)*36 + jj] - m2) * iv * gv.x + bv.x);
        o.y = f2bf((tile[(c+1)*36 + jj] - m2) * iv * gv.y + bv.y);
        o.z = f2bf((tile[(c+2)*36 + jj] - m2) * iv * gv.z + bv.z);
        o.w = f2bf((tile[(c+3)*36 + jj] - m2) * iv * gv.w + bv.w);
        *(ushort4*)(dst + (size_t)jj * CDIM + c) = o;
    }
}

// ---------------- 128x128 GEMM core, global_load_lds staging, swizzled LDS ----------------
template<bool SWAP>
__device__ __forceinline__ void gemm_core(
    const u16* __restrict__ A, int lda, const u16* __restrict__ Bw,
    int m0, int n0, u16* a_sh, u16* b_sh, f32x4 acc[4][4])
{
    const int tid  = threadIdx.x;
    const int w    = tid >> 6, lane = tid & 63;
    const int t16  = lane & 15, quad = lane >> 4;
    const int wm   = w >> 1,   wn   = w & 1;
    const int lr  = lane >> 2;                       // row within 16-row issue
    const int cbg = (lane & 3) ^ ((lane >> 3) & 3);  // swizzled col-block
    const u16* gA0 = A  + (size_t)(m0 + w*32 + lr) * lda + cbg*8;
    const u16* gA1 = gA0 + (size_t)16 * lda;
    const u16* gB0 = Bw + (size_t)(n0 + w*32 + lr) * KD + cbg*8;
    const u16* gB1 = gB0 + (size_t)16 * KD;
    u16* lA0 = a_sh + (w*32) * BK;                   // wave-uniform LDS bases
    u16* lA1 = lA0 + 16*BK;
    u16* lB0 = b_sh + (w*32) * BK;
    u16* lB1 = lB0 + 16*BK;
    const int pos = (quad ^ ((t16 >> 1) & 3)) * 8;
    const u16* ard = a_sh + (wm*64 + t16) * BK + pos;
    const u16* brd = b_sh + (wn*64 + t16) * BK + pos;
    #pragma unroll
    for (int i = 0; i < 4; i++)
        #pragma unroll
        for (int j = 0; j < 4; j++) acc[i][j] = (f32x4){0.f,0.f,0.f,0.f};
    for (int kb = 0; kb < KD; kb += BK) {
        __syncthreads();
        gld_lds16(gA0 + kb, lA0);
        gld_lds16(gA1 + kb, lA1);
        gld_lds16(gB0 + kb, lB0);
        gld_lds16(gB1 + kb, lB1);
        __syncthreads();
        s16x8 af[4], bfr[4];
        #pragma unroll
        for (int i = 0; i < 4; i++) af[i]  = *(const s16x8*)(ard + i*16*BK);
        #pragma unroll
        for (int j = 0; j < 4; j++) bfr[j] = *(const s16x8*)(brd + j*16*BK);
        #pragma unroll
        for (int i = 0; i < 4; i++)
            #pragma unroll
            for (int j = 0; j < 4; j++) {
                if (SWAP)
                    acc[i][j] = __builtin_amdgcn_mfma_f32_16x16x32_bf16(bfr[j], af[i], acc[i][j], 0,0,0);
                else
                    acc[i][j] = __builtin_amdgcn_mfma_f32_16x16x32_bf16(af[i], bfr[j], acc[i][j], 0,0,0);
            }
    }
}

// ---------------- GEMM kernels with fused epilogues ----------------
__global__ __launch_bounds__(256) void k_gemm_bu(
    const u16* __restrict__ fx, const u16* __restrict__ Wb, u16* __restrict__ Bu)
{
    __shared__ __align__(16) u16 a_sh[BM*BK], b_sh[BN*BK];
    int m0 = blockIdx.x * BM, n0 = blockIdx.y * BN;
    f32x4 acc[4][4];
    gemm_core<false>(fx, CDIM, Wb, m0, n0, a_sh, b_sh, acc);
    int lane = threadIdx.x & 63, w = threadIdx.x >> 6;
    int t16 = lane & 15, quad = lane >> 4, wm = w >> 1, wn = w & 1;
    #pragma unroll
    for (int i = 0; i < 4; i++)
        #pragma unroll
        for (int j = 0; j < 4; j++)
            #pragma unroll
            for (int rr = 0; rr < 4; rr++) {
                int m = m0 + wm*64 + i*16 + quad*4 + rr;
                int n = n0 + wn*64 + j*16 + t16;
                Bu[(size_t)m * CDIM + n] = f2bf(acc[i][j][rr]);
            }
}

__global__ __launch_bounds__(256) void k_gemm_y(
    const u16* __restrict__ xs, const u16* __restrict__ Wc,
    const u16* __restrict__ fx, const float* __restrict__ Dv, u16* __restrict__ y)
{
    __shared__ __align__(16) u16 a_sh[BM*BK], b_sh[BN*BK];
    int m0 = blockIdx.x * BM, n0 = blockIdx.y * BN;
    f32x4 acc[4][4];
    gemm_core<false>(xs, CDIM, Wc, m0, n0, a_sh, b_sh, acc);
    int lane = threadIdx.x & 63, w = threadIdx.x >> 6;
    int t16 = lane & 15, quad = lane >> 4, wm = w >> 1, wn = w & 1;
    float dv[4];
    #pragma unroll
    for (int j = 0; j < 4; j++) dv[j] = Dv[n0 + wn*64 + j*16 + t16];
    #pragma unroll
    for (int i = 0; i < 4; i++)
        #pragma unroll
        for (int j = 0; j < 4; j++)
            #pragma unroll
            for (int rr = 0; rr < 4; rr++) {
                int m = m0 + wm*64 + i*16 + quad*4 + rr;
                int n = n0 + wn*64 + j*16 + t16;
                float fxv = bf2f(fx[(size_t)m * CDIM + n]);
                float v = acc[i][j][rr] + dv[j] * fxv;
                y[(size_t)m * CDIM + n] = f2bf(gelu_fast(v) + fxv);
            }
}

// z-GEMM with fused GEGLU: block computes z1 cols [c0,c0+64) and z2 cols
// [384+c0, 384+c0+64); wn=1 waves gelu their z2 tile into LDS; wn=0 waves
// multiply and store zg[M,384] bf16.
__global__ __launch_bounds__(256) void k_gemm_zg(
    const u16* __restrict__ fy, const u16* __restrict__ We, u16* __restrict__ zg)
{
    __shared__ __align__(16) u16 sh[8448];    // a: [0,4096) b: [4096,8192); ex reuse stride 66
    u16* a_sh = sh;
    u16* b_sh = sh + BM*BK;
    const int tid = threadIdx.x;
    const int w = tid >> 6, lane = tid & 63;
    const int t16 = lane & 15, quad = lane >> 4;
    const int wm = w >> 1, wn = w & 1;
    const int m0 = blockIdx.x * BM;
    const int c0 = blockIdx.y * 64;
    const int lr  = lane >> 2;
    const int cbg = (lane & 3) ^ ((lane >> 3) & 3);
    const u16* gA0 = fy + (size_t)(m0 + w*32 + lr) * CDIM + cbg*8;
    const u16* gA1 = gA0 + (size_t)16 * CDIM;
    int brow = c0 + w*32 + ((w >= 2) ? 320 : 0);   // w0,1: z1 rows; w2,3: z2 rows (384+c0+..)
    const u16* gB0 = We + (size_t)(brow + lr) * KD + cbg*8;
    const u16* gB1 = gB0 + (size_t)16 * KD;
    u16* lA0 = a_sh + (w*32) * BK;
    u16* lA1 = lA0 + 16*BK;
    u16* lB0 = b_sh + (w*32) * BK;
    u16* lB1 = lB0 + 16*BK;
    const int pos = (quad ^ ((t16 >> 1) & 3)) * 8;
    const u16* ard = a_sh + (wm*64 + t16) * BK + pos;
    const u16* brd = b_sh + (wn*64 + t16) * BK + pos;
    f32x4 acc[4][4];
    #pragma unroll
    for (int i = 0; i < 4; i++)
        #pragma unroll
        for (int j = 0; j < 4; j++) acc[i][j] = (f32x4){0.f,0.f,0.f,0.f};
    for (int kb = 0; kb < KD; kb += BK) {
        __syncthreads();
        gld_lds16(gA0 + kb, lA0);
        gld_lds16(gA1 + kb, lA1);
        gld_lds16(gB0 + kb, lB0);
        gld_lds16(gB1 + kb, lB1);
        __syncthreads();
        s16x8 af[4], bfr[4];
        #pragma unroll
        for (int i = 0; i < 4; i++) af[i]  = *(const s16x8*)(ard + i*16*BK);
        #pragma unroll
        for (int j = 0; j < 4; j++) bfr[j] = *(const s16x8*)(brd + j*16*BK);
        #pragma unroll
        for (int i = 0; i < 4; i++)
            #pragma unroll
            for (int j = 0; j < 4; j++)
                acc[i][j] = __builtin_amdgcn_mfma_f32_16x16x32_bf16(af[i], bfr[j], acc[i][j], 0,0,0);
    }
    __syncthreads();                       // all LDS frag reads done; reuse as exchange
    if (wn == 1) {
        #pragma unroll
        for (int i = 0; i < 4; i++)
            #pragma unroll
            for (int j = 0; j < 4; j++)
                #pragma unroll
                for (int rr = 0; rr < 4; rr++) {
                    int m = wm*64 + i*16 + quad*4 + rr;
                    int c = j*16 + t16;
                    sh[m*66 + c] = f2bf(gelu_fast(acc[i][j][rr]));
                }
    }
    __syncthreads();
    if (wn == 0) {
        #pragma unroll
        for (int i = 0; i < 4; i++)
            #pragma unroll
            for (int j = 0; j < 4; j++)
                #pragma unroll
                for (int rr = 0; rr < 4; rr++) {
                    int m = wm*64 + i*16 + quad*4 + rr;
                    int c = j*16 + t16;
                    float gv = bf2f(sh[m*66 + c]);
                    zg[(size_t)(m0 + m) * CDIM + c0 + c] = f2bf(acc[i][j][rr] * gv);
                }
    }
}

__global__ __launch_bounds__(256) void k_gemm_out(
    const u16* __restrict__ zg, const u16* __restrict__ Wd,
    const u16* __restrict__ fy, float* __restrict__ out)
{
    __shared__ __align__(16) u16 a_sh[BM*BK], b_sh[BN*BK];
    int m0 = blockIdx.x * BM, n0 = blockIdx.y * BN;
    f32x4 acc[4][4];
    gemm_core<true>(zg, CDIM, Wd, m0, n0, a_sh, b_sh, acc);
    int lane = threadIdx.x & 63, w = threadIdx.x >> 6;
    int t16 = lane & 15, quad = lane >> 4, wm = w >> 1, wn = w & 1;
    int b = m0 >> 12;
    #pragma unroll
    for (int i = 0; i < 4; i++)
        #pragma unroll
        for (int j = 0; j < 4; j++)
            #pragma unroll
            for (int rr = 0; rr < 4; rr++) {
                int nn = n0 + wn*64 + j*16 + quad*4 + rr;
                int mm = m0 + wm*64 + i*16 + t16;
                float fyv = bf2f(fy[(size_t)mm * CDIM + nn]);
                int l = mm & 4095;
                out[((size_t)(b * CDIM + nn)) * LDIM + l] = acc[i][j][rr] + fyv;
            }
}

// ---------------- chunked complex scan over L (chunk=64, 64 chunks/b) ----------------
__global__ __launch_bounds__(192) void k_scan_a(
    const u16* __restrict__ Bu, const float* __restrict__ lam_bar,
    float* __restrict__ summ)
{
    int b = blockIdx.x >> 6, ch = blockIdx.x & 63;
    int p = threadIdx.x;
    float lr = lam_bar[2*p], li = lam_bar[2*p+1];
    float xr = 0.f, xi = 0.f;
    const u16* base = Bu + (size_t)(b * LDIM + ch * 64) * CDIM;
    #pragma unroll 8
    for (int i = 0; i < 64; i++) {
        float br = bf2f(base[(size_t)i * CDIM + p]);
        float bi = bf2f(base[(size_t)i * CDIM + PDIM + p]);
        float nr = lr * xr - li * xi + br;
        float ni = lr * xi + li * xr + bi;
        xr = nr; xi = ni;
    }
    size_t o = (size_t)(b * 64 + ch) * CDIM + p;
    summ[o] = xr;
    summ[o + PDIM] = xi;
}

__global__ __launch_bounds__(256) void k_scan_b(
    const float* __restrict__ lam_bar, float* __restrict__ summ)
{
    int id = blockIdx.x * 256 + threadIdx.x;
    if (id >= BSZ * PDIM) return;
    int b = id / PDIM, p = id % PDIM;
    float ar = lam_bar[2*p], ai = lam_bar[2*p+1];
    #pragma unroll
    for (int s = 0; s < 6; s++) {       // lam_bar^64
        float nr = ar * ar - ai * ai, ni = 2.f * ar * ai;
        ar = nr; ai = ni;
    }
    float cr = 0.f, ci = 0.f;
    #pragma unroll 4
    for (int ch = 0; ch < 64; ch++) {
        size_t o = (size_t)(b * 64 + ch) * CDIM + p;
        float sr = summ[o], si = summ[o + PDIM];
        summ[o] = cr; summ[o + PDIM] = ci;   // exclusive carry-in
        float nr = ar * cr - ai * ci + sr;
        float ni = ar * ci + ai * cr + si;
        cr = nr; ci = ni;
    }
}

__global__ __launch_bounds__(192) void k_scan_c(
    u16* __restrict__ Bu, const float* __restrict__ lam_bar,
    const float* __restrict__ summ)
{
    int b = blockIdx.x >> 6, ch = blockIdx.x & 63;
    int p = threadIdx.x;
    float lr = lam_bar[2*p], li = lam_bar[2*p+1];
    size_t oc = (size_t)(b * 64 + ch) * CDIM + p;
    float xr = summ[oc], xi = summ[oc + PDIM];
    u16* base = Bu + (size_t)(b * LDIM + ch * 64) * CDIM;
    #pragma unroll 8
    for (int i = 0; i < 64; i++) {
        float br = bf2f(base[(size_t)i * CDIM + p]);
        float bi = bf2f(base[(size_t)i * CDIM + PDIM + p]);
        float nr = lr * xr - li * xi + br;
        float ni = lr * xi + li * xr + bi;
        xr = nr; xi = ni;
        base[(size_t)i * CDIM + p] = f2bf(xr);
        base[(size_t)i * CDIM + PDIM + p] = f2bf(xi);
    }
}

// ---------------- LN2 (rows contiguous, bf16 in/out) ----------------
__global__ __launch_bounds__(256) void k_ln2(
    const u16* __restrict__ y, const float* __restrict__ g,
    const float* __restrict__ bb, u16* __restrict__ fy)
{
    int w = threadIdx.x >> 6, lane = threadIdx.x & 63;
    size_t m = (size_t)blockIdx.x * 4 + w;
    const u16* row = y + m * CDIM;
    float v[6];
    float sum = 0.f, sq = 0.f;
    #pragma unroll
    for (int i = 0; i < 6; i++) {
        v[i] = bf2f(row[lane + 64 * i]);
        sum += v[i]; sq += v[i] * v[i];
    }
    #pragma unroll
    for (int o = 1; o < 64; o <<= 1) {
        sum += __shfl_xor(sum, o); sq += __shfl_xor(sq, o);
    }
    float mu  = sum * (1.0f / CDIM);
    float var = sq * (1.0f / CDIM) - mu * mu;
    float inv = rsqrtf(var + 1e-5f);
    u16* dst = fy + m * CDIM;
    #pragma unroll
    for (int i = 0; i < 6; i++) {
        int c = lane + 64 * i;
        dst[c] = f2bf((v[i] - mu) * inv * g[c] + bb[c]);
    }
}

extern "C" void kernel_launch(void* const* d_in, const int* in_sizes, int n_in,
                              void* d_out, int out_size, void* d_ws, size_t ws_size,
                              hipStream_t stream)
{
    const float* x        = (const float*)d_in[0];
    const float* ln1_g    = (const float*)d_in[1];
    const float* ln1_b    = (const float*)d_in[2];
    const float* Lambda   = (const float*)d_in[3];
    const float* Bmat     = (const float*)d_in[4];
    const float* Cmat     = (const float*)d_in[5];
    const float* Dvec     = (const float*)d_in[6];
    const float* log_step = (const float*)d_in[7];
    const float* ln2_g    = (const float*)d_in[8];
    const float* ln2_b    = (const float*)d_in[9];
    const float* W_enc    = (const float*)d_in[10];
    const float* W_dec    = (const float*)d_in[11];

    char* ws = (char*)d_ws;
    const size_t HBF = (size_t)MDIM * CDIM * 2;    // 50,331,648 B (bf16 [M,384])
    u16* fx = (u16*)(ws);                          // fx bf16
    u16* fy = (u16*)(ws + HBF);                    // fy bf16
    u16* bu = (u16*)(ws + 2 * HBF);                // Bu/xs bf16 [M,384]
    u16* zg = (u16*)(ws + 2 * HBF);                // zg bf16 [M,384] (aliases bu; bu dead)
    char* wbase = ws + 3 * HBF;
    u16* Wb = (u16*)(wbase);
    u16* Wc = (u16*)(wbase + 294912);
    u16* We = (u16*)(wbase + 589824);
    u16* Wd = (u16*)(wbase + 1179648);
    float* lam_bar = (float*)(wbase + 1474560);
    float* summ    = (float*)(wbase + 1476096);    // 16*64*384 fp32
    u16* yb  = (u16*)d_out;                        // y bf16 scratch inside d_out
    float* out = (float*)d_out;

    k_setup<<<2305, 256, 0, stream>>>(Lambda, Bmat, Cmat, log_step, W_enc, W_dec,
                                      Wb, Wc, We, Wd, lam_bar);
    k_ln1<<<2048, 256, 0, stream>>>(x, ln1_g, ln1_b, fx);
    k_gemm_bu<<<dim3(512, 3), 256, 0, stream>>>(fx, Wb, bu);
    k_scan_a<<<1024, 192, 0, stream>>>(bu, lam_bar, summ);
    k_scan_b<<<12, 256, 0, stream>>>(lam_bar, summ);
    k_scan_c<<<1024, 192, 0, stream>>>(bu, lam_bar, summ);
    k_gemm_y<<<dim3(512, 3), 256, 0, stream>>>(bu, Wc, fx, Dvec, yb);
    k_ln2<<<16384, 256, 0, stream>>>(yb, ln2_g, ln2_b, fy);
    k_gemm_zg<<<dim3(512, 6), 256, 0, stream>>>(fy, We, zg);
    k_gemm_out<<<dim3(512, 3), 256, 0, stream>>>(zg, Wd, fy, out);
}